// Round 1
// baseline (770.925 us; speedup 1.0000x reference)
//
#include <hip/hip_runtime.h>
#include <math.h>

#define BB 2
#define SS 4096
#define HH 768
#define NHEADS 12
#define HDIM 64
#define MTOT (BB*SS)     // 8192
#define NQKV (3*HH)      // 2304

// ---------------- GEMM: C[M,N] = A[M,K] * W[N,K]^T (all row-major) --------
template<int BM, int BN, int BK>
__global__ __launch_bounds__(256)
void gemm_xwt(const float* __restrict__ A, const float* __restrict__ W,
              float* __restrict__ C, int M, int N, int K) {
  __shared__ __align__(16) float As[BK][BM];
  __shared__ __align__(16) float Bs[BK][BN];
  const int tid = threadIdx.x;
  const int bm = blockIdx.x * BM;
  const int bn = blockIdx.y * BN;
  const int tx = tid & 15, ty = tid >> 4;   // 16x16 thread grid, 8x8 microtile
  float acc[8][8];
#pragma unroll
  for (int i = 0; i < 8; ++i)
#pragma unroll
    for (int j = 0; j < 8; ++j) acc[i][j] = 0.f;

  constexpr int F4R = BK / 4;   // float4 per row-chunk
  for (int k0 = 0; k0 < K; k0 += BK) {
#pragma unroll
    for (int i = 0; i < (BM * BK) / (4 * 256); ++i) {
      int idx = tid + i * 256;
      int row = idx / F4R;
      int kc = (idx % F4R) * 4;
      float4 v = *reinterpret_cast<const float4*>(&A[(size_t)(bm + row) * K + k0 + kc]);
      As[kc + 0][row] = v.x; As[kc + 1][row] = v.y;
      As[kc + 2][row] = v.z; As[kc + 3][row] = v.w;
    }
#pragma unroll
    for (int i = 0; i < (BN * BK) / (4 * 256); ++i) {
      int idx = tid + i * 256;
      int row = idx / F4R;
      int kc = (idx % F4R) * 4;
      float4 v = *reinterpret_cast<const float4*>(&W[(size_t)(bn + row) * K + k0 + kc]);
      Bs[kc + 0][row] = v.x; Bs[kc + 1][row] = v.y;
      Bs[kc + 2][row] = v.z; Bs[kc + 3][row] = v.w;
    }
    __syncthreads();
#pragma unroll
    for (int kk = 0; kk < BK; ++kk) {
      float4 a0 = *reinterpret_cast<const float4*>(&As[kk][ty * 8]);
      float4 a1 = *reinterpret_cast<const float4*>(&As[kk][ty * 8 + 4]);
      float4 b0 = *reinterpret_cast<const float4*>(&Bs[kk][tx * 8]);
      float4 b1 = *reinterpret_cast<const float4*>(&Bs[kk][tx * 8 + 4]);
      float ra[8] = {a0.x, a0.y, a0.z, a0.w, a1.x, a1.y, a1.z, a1.w};
      float rb[8] = {b0.x, b0.y, b0.z, b0.w, b1.x, b1.y, b1.z, b1.w};
#pragma unroll
      for (int i = 0; i < 8; ++i)
#pragma unroll
        for (int j = 0; j < 8; ++j) acc[i][j] += ra[i] * rb[j];
    }
    __syncthreads();
  }
#pragma unroll
  for (int i = 0; i < 8; ++i) {
#pragma unroll
    for (int j = 0; j < 8; j += 4) {
      float4 v;
      v.x = acc[i][j]; v.y = acc[i][j + 1]; v.z = acc[i][j + 2]; v.w = acc[i][j + 3];
      *reinterpret_cast<float4*>(&C[(size_t)(bm + ty * 8 + i) * N + bn + tx * 8 + j]) = v;
    }
  }
}

// ---------------- RoPE cos/sin table: [4096][32] each, computed in f64 ----
__global__ void rope_table_kernel(float* __restrict__ ctab, float* __restrict__ stab) {
  int idx = blockIdx.x * 256 + threadIdx.x;   // 4096*32 = 131072
  if (idx >= SS * 32) return;
  int s = idx >> 5;
  int j = idx & 31;
  double inv = pow(10000.0, -(double)j / 32.0);
  double ph = (double)s * inv;
  ctab[idx] = (float)cos(ph);
  stab[idx] = (float)sin(ph);
}

// ---------------- RoPE in-place on q,k parts of qkv ----------------------
__global__ __launch_bounds__(256)
void rope_kernel(float* __restrict__ qkv, const int* __restrict__ pos,
                 const float* __restrict__ ctab, const float* __restrict__ stab) {
  int idx = blockIdx.x * 256 + threadIdx.x;   // MTOT*NHEADS*32
  int d2 = idx & 31;
  int h = (idx >> 5) % NHEADS;
  int m = idx / (32 * NHEADS);
  int s = pos[m];
  float c = ctab[s * 32 + d2];
  float sn = stab[s * 32 + d2];
  size_t base = (size_t)m * NQKV + h * 64 + d2;
  float q1 = qkv[base], q2 = qkv[base + 32];
  qkv[base] = q1 * c - q2 * sn;
  qkv[base + 32] = q2 * c + q1 * sn;
  float k1 = qkv[base + HH], k2 = qkv[base + HH + 32];
  qkv[base + HH] = k1 * c - k2 * sn;
  qkv[base + HH + 32] = k2 * c + k1 * sn;
}

// ---------------- Sliding-window attention -------------------------------
// Block handles (b, head, 16-query tile). Window: |key - q| <= 64.
#define QT 16
#define KT 144          // 16 + 128
#define KPAD 65         // bank = (r*65+d)%32 = (r+d)%32 -> conflict-free

__global__ __launch_bounds__(256)
void attn_kernel(const float* __restrict__ qkv, float* __restrict__ out) {
  __shared__ __align__(16) float Qs[QT][HDIM];
  __shared__ float Ks[KT][KPAD];     // reused for V
  __shared__ float Ps[QT][KT + 1];

  const int blk = blockIdx.x;
  const int qt = blk % (SS / QT);
  const int h = (blk / (SS / QT)) % NHEADS;
  const int b = blk / ((SS / QT) * NHEADS);
  const int q0 = qt * QT;
  const int tid = threadIdx.x;
  const int kbase = q0 - 64;

  // Load Q tile (scaled by 1/sqrt(64)): 16 rows x 64 = 256 float4
  {
    int r = tid >> 4;
    int dc = (tid & 15) * 4;
    const float* src = &qkv[((size_t)b * SS + q0 + r) * NQKV + h * 64 + dc];
    float4 v = *reinterpret_cast<const float4*>(src);
    const float sc = 0.125f;
    *reinterpret_cast<float4*>(&Qs[r][dc]) =
        make_float4(v.x * sc, v.y * sc, v.z * sc, v.w * sc);
  }
  // Load K tile: 144 rows x 64 = 2304 float4, 9 per thread (zero OOB rows)
#pragma unroll
  for (int i = 0; i < 9; ++i) {
    int idx = tid + i * 256;
    int r = idx >> 4;
    int dc = (idx & 15) * 4;
    int key = kbase + r;
    float4 v = make_float4(0.f, 0.f, 0.f, 0.f);
    if (key >= 0 && key < SS)
      v = *reinterpret_cast<const float4*>(
          &qkv[((size_t)b * SS + key) * NQKV + HH + h * 64 + dc]);
    Ks[r][dc] = v.x; Ks[r][dc + 1] = v.y; Ks[r][dc + 2] = v.z; Ks[r][dc + 3] = v.w;
  }
  __syncthreads();

  // Scores: 16x144 entries, 9 per thread
#pragma unroll
  for (int i = 0; i < 9; ++i) {
    int e = tid + i * 256;
    int qi = e / KT;
    int r = e % KT;
    int key = kbase + r;
    float sc = -1e30f;
    if (r >= qi && r <= qi + 128 && key >= 0 && key < SS) {
      float acc = 0.f;
#pragma unroll
      for (int d = 0; d < HDIM; d += 4) {
        acc += Qs[qi][d] * Ks[r][d];
        acc += Qs[qi][d + 1] * Ks[r][d + 1];
        acc += Qs[qi][d + 2] * Ks[r][d + 2];
        acc += Qs[qi][d + 3] * Ks[r][d + 3];
      }
      sc = acc;
    }
    Ps[qi][r] = sc;
  }
  __syncthreads();

  // Softmax per row: 16 threads per row (contiguous 16-lane groups)
  {
    int row = tid >> 4;
    int l16 = tid & 15;
    float mx = -1e30f;
    for (int i = l16; i < KT; i += 16) mx = fmaxf(mx, Ps[row][i]);
#pragma unroll
    for (int m = 8; m >= 1; m >>= 1) mx = fmaxf(mx, __shfl_xor(mx, m));
    float sum = 0.f;
    float pv[9];
    int cnt = 0;
    for (int i = l16; i < KT; i += 16) {
      float p = __expf(Ps[row][i] - mx);
      pv[cnt++] = p;
      sum += p;
    }
#pragma unroll
    for (int m = 8; m >= 1; m >>= 1) sum += __shfl_xor(sum, m);
    float inv = 1.0f / sum;
    cnt = 0;
    for (int i = l16; i < KT; i += 16) Ps[row][i] = pv[cnt++] * inv;
  }
  // Load V tile into Ks (K reads finished at prior barrier)
#pragma unroll
  for (int i = 0; i < 9; ++i) {
    int idx = tid + i * 256;
    int r = idx >> 4;
    int dc = (idx & 15) * 4;
    int key = kbase + r;
    float4 v = make_float4(0.f, 0.f, 0.f, 0.f);
    if (key >= 0 && key < SS)
      v = *reinterpret_cast<const float4*>(
          &qkv[((size_t)b * SS + key) * NQKV + 2 * HH + h * 64 + dc]);
    Ks[r][dc] = v.x; Ks[r][dc + 1] = v.y; Ks[r][dc + 2] = v.z; Ks[r][dc + 3] = v.w;
  }
  __syncthreads();

  // PV: outputs 16x64, 4 per thread
#pragma unroll
  for (int i = 0; i < 4; ++i) {
    int e = tid + i * 256;
    int qi = e >> 6;
    int d = e & 63;
    float acc = 0.f;
    for (int r = 0; r < KT; ++r) acc += Ps[qi][r] * Ks[r][d];
    out[((size_t)b * SS + q0 + qi) * HH + h * 64 + d] = acc;
  }
}

extern "C" void kernel_launch(void* const* d_in, const int* in_sizes, int n_in,
                              void* d_out, int out_size, void* d_ws, size_t ws_size,
                              hipStream_t stream) {
  const float* hs = (const float*)d_in[0];
  const int* pos = (const int*)d_in[3];
  const float* Wqkv = (const float*)d_in[4];
  const float* Wo = (const float*)d_in[5];
  float* out = (float*)d_out;

  float* qkv = (float*)d_ws;                                // 8192*2304 f32
  float* attn = qkv + (size_t)MTOT * NQKV;                  // 8192*768 f32
  float* ctab = attn + (size_t)MTOT * HH;                   // 4096*32
  float* stab = ctab + (size_t)SS * 32;                     // 4096*32

  // 1. QKV projection
  gemm_xwt<128, 128, 16><<<dim3(MTOT / 128, NQKV / 128), 256, 0, stream>>>(
      hs, Wqkv, qkv, MTOT, NQKV, HH);
  // 2. RoPE tables + apply
  rope_table_kernel<<<(SS * 32 + 255) / 256, 256, 0, stream>>>(ctab, stab);
  rope_kernel<<<(MTOT * NHEADS * 32) / 256, 256, 0, stream>>>(qkv, pos, ctab, stab);
  // 3. Sliding-window attention
  attn_kernel<<<BB * NHEADS * (SS / QT), 256, 0, stream>>>(qkv, attn);
  // 4. Output projection
  gemm_xwt<128, 128, 16><<<dim3(MTOT / 128, HH / 128), 256, 0, stream>>>(
      attn, Wo, out, MTOT, HH, HH);
}

// Round 2
// 449.550 us; speedup vs baseline: 1.7149x; 1.7149x over previous
//
#include <hip/hip_runtime.h>
#include <hip/hip_bf16.h>
#include <math.h>

#define BB 2
#define SS 4096
#define HH 768
#define NHEADS 12
#define HDIM 64
#define MTOT (BB*SS)     // 8192
#define NQKV (3*HH)      // 2304

typedef __hip_bfloat16 bf16;
typedef __attribute__((ext_vector_type(8))) short bf16x8s;
typedef __attribute__((ext_vector_type(4))) float f32x4;

__device__ __forceinline__ void gld_lds16(const void* g, void* l) {
  __builtin_amdgcn_global_load_lds(
      (const __attribute__((address_space(1))) unsigned int*)g,
      (__attribute__((address_space(3))) unsigned int*)l, 16, 0, 0);
}

// ---------------- split f32 -> bf16 hi/lo --------------------------------
__global__ __launch_bounds__(256)
void split_kernel(const float* __restrict__ src, bf16* __restrict__ hi,
                  bf16* __restrict__ lo, int n4) {
  int i = blockIdx.x * 256 + threadIdx.x;
  if (i >= n4) return;
  float4 v = reinterpret_cast<const float4*>(src)[i];
  float vv[4] = {v.x, v.y, v.z, v.w};
  ushort4 hb, lb;
  unsigned short* hp = &hb.x;
  unsigned short* lp = &lb.x;
#pragma unroll
  for (int j = 0; j < 4; ++j) {
    bf16 h = __float2bfloat16(vv[j]);
    float hf = __bfloat162float(h);
    bf16 l = __float2bfloat16(vv[j] - hf);
    hp[j] = *reinterpret_cast<unsigned short*>(&h);
    lp[j] = *reinterpret_cast<unsigned short*>(&l);
  }
  reinterpret_cast<ushort4*>(hi)[i] = hb;
  reinterpret_cast<ushort4*>(lo)[i] = lb;
}

// ---------------- MFMA GEMM: C[M,N] = (Ahi+Alo)(Bhi+Blo)^T, 3-pass -------
// A: [M][K] bf16 (hi/lo), B: [N][K] bf16 (hi/lo), C: [M][N] f32. K%32==0.
__global__ __launch_bounds__(256)
void gemm_mfma(const bf16* __restrict__ Ahi, const bf16* __restrict__ Alo,
               const bf16* __restrict__ Bhi, const bf16* __restrict__ Blo,
               float* __restrict__ C, int Mtiles, int N, int K) {
  __shared__ __align__(16) bf16 As[128][32];   // 8 KB
  __shared__ __align__(16) bf16 Bs[128][32];   // 8 KB
  const int tid = threadIdx.x;
  const int lane = tid & 63;
  const int w = tid >> 6;
  const int wr = w >> 1, wc = w & 1;

  // XCD-aware bijective swizzle (nwg % 8 == 0 for both call sites)
  const int nwg = gridDim.x;
  const int bid = blockIdx.x;
  const int swz = (bid & 7) * (nwg >> 3) + (bid >> 3);
  const int bm = (swz % Mtiles) * 128;
  const int bn = (swz / Mtiles) * 128;

  f32x4 acc[4][4] = {};

  const int l4 = lane >> 2;      // row-sub within 16
  const int lk = lane & 3;       // which 16B chunk of the 64B row
  const int srow = w * 32;       // wave's staging row base

  const bf16* Aseg[3] = {Ahi, Alo, Ahi};
  const bf16* Bseg[3] = {Bhi, Bhi, Blo};

#pragma unroll
  for (int seg = 0; seg < 3; ++seg) {
    const bf16* Ab = Aseg[seg];
    const bf16* Bb = Bseg[seg];
    for (int k0 = 0; k0 < K; k0 += 32) {
#pragma unroll
      for (int i = 0; i < 2; ++i) {
        int row = srow + i * 16 + l4;
        gld_lds16(Ab + (size_t)(bm + row) * K + k0 + lk * 8,
                  (char*)&As[0][0] + w * 2048 + i * 1024 + lane * 16);
        gld_lds16(Bb + (size_t)(bn + row) * K + k0 + lk * 8,
                  (char*)&Bs[0][0] + w * 2048 + i * 1024 + lane * 16);
      }
      __syncthreads();
      bf16x8s av[4], bv[4];
#pragma unroll
      for (int m = 0; m < 4; ++m)
        av[m] = *reinterpret_cast<const bf16x8s*>(
            &As[wr * 64 + m * 16 + (lane & 15)][(lane >> 4) * 8]);
#pragma unroll
      for (int n = 0; n < 4; ++n)
        bv[n] = *reinterpret_cast<const bf16x8s*>(
            &Bs[wc * 64 + n * 16 + (lane & 15)][(lane >> 4) * 8]);
#pragma unroll
      for (int m = 0; m < 4; ++m)
#pragma unroll
        for (int n = 0; n < 4; ++n)
          acc[m][n] = __builtin_amdgcn_mfma_f32_16x16x32_bf16(av[m], bv[n],
                                                              acc[m][n], 0, 0, 0);
      __syncthreads();
    }
  }
  // epilogue: C/D layout col=lane&15, row=(lane>>4)*4+reg
  const int cl = lane & 15;
  const int rg = lane >> 4;
#pragma unroll
  for (int m = 0; m < 4; ++m)
#pragma unroll
    for (int n = 0; n < 4; ++n)
#pragma unroll
      for (int r = 0; r < 4; ++r) {
        int row = bm + wr * 64 + m * 16 + rg * 4 + r;
        int col = bn + wc * 64 + n * 16 + cl;
        C[(size_t)row * N + col] = acc[m][n][r];
      }
}

// ---------------- RoPE cos/sin table (f64 phase, f32 trig) ---------------
__global__ void rope_table_kernel(float* __restrict__ ctab, float* __restrict__ stab) {
  int idx = blockIdx.x * 256 + threadIdx.x;   // 4096*32
  if (idx >= SS * 32) return;
  int s = idx >> 5;
  int j = idx & 31;
  const double r = 0.7498942093324559;  // 10000^(-1/32), exact double
  double inv = 1.0;
  for (int t = 0; t < j; ++t) inv *= r;
  double ph = (double)s * inv;
  const double TWO_PI = 6.283185307179586;
  double red = ph - TWO_PI * floor(ph / TWO_PI);
  float rf = (float)red;
  ctab[idx] = cosf(rf);
  stab[idx] = sinf(rf);
}

// ---------------- RoPE in-place on q,k parts of qkv ----------------------
__global__ __launch_bounds__(256)
void rope_kernel(float* __restrict__ qkv, const int* __restrict__ pos,
                 const float* __restrict__ ctab, const float* __restrict__ stab) {
  int idx = blockIdx.x * 256 + threadIdx.x;   // MTOT*NHEADS*32
  int d2 = idx & 31;
  int h = (idx >> 5) % NHEADS;
  int m = idx / (32 * NHEADS);
  int s = pos[m];
  float c = ctab[s * 32 + d2];
  float sn = stab[s * 32 + d2];
  size_t base = (size_t)m * NQKV + h * 64 + d2;
  float q1 = qkv[base], q2 = qkv[base + 32];
  qkv[base] = q1 * c - q2 * sn;
  qkv[base + 32] = q2 * c + q1 * sn;
  float k1 = qkv[base + HH], k2 = qkv[base + HH + 32];
  qkv[base + HH] = k1 * c - k2 * sn;
  qkv[base + HH + 32] = k2 * c + k1 * sn;
}

// ---------------- Sliding-window attention -------------------------------
#define QT 16
#define KT 144          // 16 + 128
#define KPAD 65

__global__ __launch_bounds__(256)
void attn_kernel(const float* __restrict__ qkv, bf16* __restrict__ ahi,
                 bf16* __restrict__ alo) {
  __shared__ __align__(16) float Qs[QT][HDIM];
  __shared__ float Ks[KT][KPAD];
  __shared__ float Ps[QT][KT + 1];

  const int blk = blockIdx.x;
  const int qt = blk % (SS / QT);
  const int h = (blk / (SS / QT)) % NHEADS;
  const int b = blk / ((SS / QT) * NHEADS);
  const int q0 = qt * QT;
  const int tid = threadIdx.x;
  const int kbase = q0 - 64;

  {
    int r = tid >> 4;
    int dc = (tid & 15) * 4;
    const float* src = &qkv[((size_t)b * SS + q0 + r) * NQKV + h * 64 + dc];
    float4 v = *reinterpret_cast<const float4*>(src);
    const float sc = 0.125f;
    *reinterpret_cast<float4*>(&Qs[r][dc]) =
        make_float4(v.x * sc, v.y * sc, v.z * sc, v.w * sc);
  }
#pragma unroll
  for (int i = 0; i < 9; ++i) {
    int idx = tid + i * 256;
    int r = idx >> 4;
    int dc = (idx & 15) * 4;
    int key = kbase + r;
    float4 v = make_float4(0.f, 0.f, 0.f, 0.f);
    if (key >= 0 && key < SS)
      v = *reinterpret_cast<const float4*>(
          &qkv[((size_t)b * SS + key) * NQKV + HH + h * 64 + dc]);
    Ks[r][dc] = v.x; Ks[r][dc + 1] = v.y; Ks[r][dc + 2] = v.z; Ks[r][dc + 3] = v.w;
  }
  __syncthreads();

#pragma unroll
  for (int i = 0; i < 9; ++i) {
    int e = tid + i * 256;
    int qi = e / KT;
    int r = e % KT;
    int key = kbase + r;
    float sc = -1e30f;
    if (r >= qi && r <= qi + 128 && key >= 0 && key < SS) {
      float acc = 0.f;
#pragma unroll
      for (int d = 0; d < HDIM; d += 4) {
        acc += Qs[qi][d] * Ks[r][d];
        acc += Qs[qi][d + 1] * Ks[r][d + 1];
        acc += Qs[qi][d + 2] * Ks[r][d + 2];
        acc += Qs[qi][d + 3] * Ks[r][d + 3];
      }
      sc = acc;
    }
    Ps[qi][r] = sc;
  }
  __syncthreads();

  {
    int row = tid >> 4;
    int l16 = tid & 15;
    float mx = -1e30f;
    for (int i = l16; i < KT; i += 16) mx = fmaxf(mx, Ps[row][i]);
#pragma unroll
    for (int m = 8; m >= 1; m >>= 1) mx = fmaxf(mx, __shfl_xor(mx, m));
    float sum = 0.f;
    float pv[9];
    int cnt = 0;
    for (int i = l16; i < KT; i += 16) {
      float p = __expf(Ps[row][i] - mx);
      pv[cnt++] = p;
      sum += p;
    }
#pragma unroll
    for (int m = 8; m >= 1; m >>= 1) sum += __shfl_xor(sum, m);
    float inv = 1.0f / sum;
    cnt = 0;
    for (int i = l16; i < KT; i += 16) Ps[row][i] = pv[cnt++] * inv;
  }
#pragma unroll
  for (int i = 0; i < 9; ++i) {
    int idx = tid + i * 256;
    int r = idx >> 4;
    int dc = (idx & 15) * 4;
    int key = kbase + r;
    float4 v = make_float4(0.f, 0.f, 0.f, 0.f);
    if (key >= 0 && key < SS)
      v = *reinterpret_cast<const float4*>(
          &qkv[((size_t)b * SS + key) * NQKV + 2 * HH + h * 64 + dc]);
    Ks[r][dc] = v.x; Ks[r][dc + 1] = v.y; Ks[r][dc + 2] = v.z; Ks[r][dc + 3] = v.w;
  }
  __syncthreads();

#pragma unroll
  for (int i = 0; i < 4; ++i) {
    int e = tid + i * 256;
    int qi = e >> 6;
    int d = e & 63;
    float acc = 0.f;
    for (int r = 0; r < KT; ++r) acc += Ps[qi][r] * Ks[r][d];
    size_t oidx = ((size_t)b * SS + q0 + qi) * HH + h * 64 + d;
    bf16 hv = __float2bfloat16(acc);
    float hf = __bfloat162float(hv);
    ahi[oidx] = hv;
    alo[oidx] = __float2bfloat16(acc - hf);
  }
}

extern "C" void kernel_launch(void* const* d_in, const int* in_sizes, int n_in,
                              void* d_out, int out_size, void* d_ws, size_t ws_size,
                              hipStream_t stream) {
  const float* hs = (const float*)d_in[0];
  const int* pos = (const int*)d_in[3];
  const float* Wqkv = (const float*)d_in[4];
  const float* Wo = (const float*)d_in[5];
  float* out = (float*)d_out;

  uint8_t* ws = (uint8_t*)d_ws;
  size_t off = 0;
  float* qkv = (float*)(ws + off); off += (size_t)MTOT * NQKV * 4;        // 75.5 MB
  float* ctab = (float*)(ws + off); off += (size_t)SS * 32 * 4;
  float* stab = (float*)(ws + off); off += (size_t)SS * 32 * 4;
  bf16* hs_hi = (bf16*)(ws + off); off += (size_t)MTOT * HH * 2;
  bf16* hs_lo = (bf16*)(ws + off); off += (size_t)MTOT * HH * 2;
  bf16* wq_hi = (bf16*)(ws + off); off += (size_t)NQKV * HH * 2;
  bf16* wq_lo = (bf16*)(ws + off); off += (size_t)NQKV * HH * 2;
  bf16* wo_hi = (bf16*)(ws + off); off += (size_t)HH * HH * 2;
  bf16* wo_lo = (bf16*)(ws + off); off += (size_t)HH * HH * 2;
  bf16* at_hi = (bf16*)(ws + off); off += (size_t)MTOT * HH * 2;
  bf16* at_lo = (bf16*)(ws + off); off += (size_t)MTOT * HH * 2;

  // splits
  split_kernel<<<(MTOT * HH / 4 + 255) / 256, 256, 0, stream>>>(hs, hs_hi, hs_lo,
                                                                MTOT * HH / 4);
  split_kernel<<<(NQKV * HH / 4 + 255) / 256, 256, 0, stream>>>(Wqkv, wq_hi, wq_lo,
                                                                NQKV * HH / 4);
  split_kernel<<<(HH * HH / 4 + 255) / 256, 256, 0, stream>>>(Wo, wo_hi, wo_lo,
                                                              HH * HH / 4);
  rope_table_kernel<<<(SS * 32 + 255) / 256, 256, 0, stream>>>(ctab, stab);

  // 1. QKV projection (MFMA, 3-pass split-bf16)
  gemm_mfma<<<(MTOT / 128) * (NQKV / 128), 256, 0, stream>>>(
      hs_hi, hs_lo, wq_hi, wq_lo, qkv, MTOT / 128, NQKV, HH);
  // 2. RoPE
  rope_kernel<<<(MTOT * NHEADS * 32) / 256, 256, 0, stream>>>(qkv, pos, ctab, stab);
  // 3. Attention (writes hi/lo bf16 for GEMM2)
  attn_kernel<<<BB * NHEADS * (SS / QT), 256, 0, stream>>>(qkv, at_hi, at_lo);
  // 4. Output projection (MFMA, 3-pass split-bf16)
  gemm_mfma<<<(MTOT / 128) * (HH / 128), 256, 0, stream>>>(
      at_hi, at_lo, wo_hi, wo_lo, out, MTOT / 128, HH, HH);
}

// Round 3
// 146.850 us; speedup vs baseline: 5.2497x; 3.0613x over previous
//
#include <hip/hip_runtime.h>
#include <hip/hip_bf16.h>
#include <math.h>

#define BB 2
#define SS 4096
#define HH 768
#define NHEADS 12
#define MTOT (BB*SS)     // 8192
#define NQKV (3*HH)      // 2304

typedef _Float16 f16;
typedef __attribute__((ext_vector_type(8))) _Float16 f16x8;
typedef __attribute__((ext_vector_type(4))) _Float16 f16x4;
typedef __attribute__((ext_vector_type(4))) float f32x4;

__device__ __forceinline__ void gld_lds16(const void* g, void* l) {
  __builtin_amdgcn_global_load_lds(
      (const __attribute__((address_space(1))) unsigned int*)g,
      (__attribute__((address_space(3))) unsigned int*)l, 16, 0, 0);
}

// ---------------- f32 -> f16 convert -------------------------------------
__global__ __launch_bounds__(256)
void cvt_kernel(const float* __restrict__ src, f16* __restrict__ dst, int n4) {
  int i = blockIdx.x * 256 + threadIdx.x;
  if (i >= n4) return;
  float4 v = reinterpret_cast<const float4*>(src)[i];
  f16x4 o;
  o[0] = (f16)v.x; o[1] = (f16)v.y; o[2] = (f16)v.z; o[3] = (f16)v.w;
  reinterpret_cast<f16x4*>(dst)[i] = o;
}

// ---------------- RoPE cos/sin table (f64 phase) -------------------------
__global__ void rope_table_kernel(float* __restrict__ ctab, float* __restrict__ stab) {
  int idx = blockIdx.x * 256 + threadIdx.x;   // 4096*32
  if (idx >= SS * 32) return;
  int s = idx >> 5;
  int j = idx & 31;
  const double r = 0.7498942093324559;  // 10000^(-1/32)
  double inv = 1.0;
  for (int t = 0; t < j; ++t) inv *= r;
  double ph = (double)s * inv;
  const double TWO_PI = 6.283185307179586;
  double red = ph - TWO_PI * floor(ph / TWO_PI);
  float rf = (float)red;
  ctab[idx] = cosf(rf);
  stab[idx] = sinf(rf);
}

// ---------------- f16 MFMA GEMM: C = A * W^T -----------------------------
// EPI=0: write f32 C.  EPI=1: fused RoPE epilogue -> q/k/v f16 buffers.
template<int EPI>
__global__ __launch_bounds__(256)
void gemm_f16(const f16* __restrict__ A, const f16* __restrict__ Bw,
              float* __restrict__ C,
              f16* __restrict__ Oq, f16* __restrict__ Ok, f16* __restrict__ Ov,
              const int* __restrict__ pos,
              const float* __restrict__ ctab, const float* __restrict__ stab,
              int Mtiles, int N, int K) {
  __shared__ __align__(16) f16 As[128][32];   // 8 KB
  __shared__ __align__(16) f16 Bs[128][32];   // 8 KB
  const int tid = threadIdx.x;
  const int lane = tid & 63;
  const int w = tid >> 6;
  const int wr = w >> 1, wc = w & 1;

  const int nwg = gridDim.x;
  const int bid = blockIdx.x;
  const int swz = (bid & 7) * (nwg >> 3) + (bid >> 3);
  const int bm = (swz % Mtiles) * 128;
  const int bn = (swz / Mtiles) * 128;

  f32x4 acc[4][4] = {};

  const int l4 = lane >> 2;
  const int lk = lane & 3;
  const int srow = w * 32;

  for (int k0 = 0; k0 < K; k0 += 32) {
#pragma unroll
    for (int i = 0; i < 2; ++i) {
      int row = srow + i * 16 + l4;
      gld_lds16(A + (size_t)(bm + row) * K + k0 + lk * 8,
                (char*)&As[0][0] + w * 2048 + i * 1024 + lane * 16);
      gld_lds16(Bw + (size_t)(bn + row) * K + k0 + lk * 8,
                (char*)&Bs[0][0] + w * 2048 + i * 1024 + lane * 16);
    }
    __syncthreads();
    f16x8 av[4], bv[4];
#pragma unroll
    for (int m = 0; m < 4; ++m)
      av[m] = *reinterpret_cast<const f16x8*>(
          &As[wr * 64 + m * 16 + (lane & 15)][(lane >> 4) * 8]);
#pragma unroll
    for (int n = 0; n < 4; ++n)
      bv[n] = *reinterpret_cast<const f16x8*>(
          &Bs[wc * 64 + n * 16 + (lane & 15)][(lane >> 4) * 8]);
#pragma unroll
    for (int m = 0; m < 4; ++m)
#pragma unroll
      for (int n = 0; n < 4; ++n)
        acc[m][n] = __builtin_amdgcn_mfma_f32_16x16x32_f16(av[m], bv[n],
                                                           acc[m][n], 0, 0, 0);
    __syncthreads();
  }

  const int cl = lane & 15;
  const int rg = lane >> 4;
  if (EPI == 0) {
#pragma unroll
    for (int m = 0; m < 4; ++m)
#pragma unroll
      for (int n = 0; n < 4; ++n)
#pragma unroll
        for (int r = 0; r < 4; ++r) {
          int row = bm + wr * 64 + m * 16 + rg * 4 + r;
          int col = bn + wc * 64 + n * 16 + cl;
          C[(size_t)row * N + col] = acc[m][n][r];
        }
  } else {
    const int sec = bn / HH;        // 0=q 1=k 2=v (uniform per block)
    f16* dst = (sec == 0) ? Oq : ((sec == 1) ? Ok : Ov);
    const int hb = bn - sec * HH + wc * 64;
#pragma unroll
    for (int m = 0; m < 4; ++m)
#pragma unroll
      for (int r = 0; r < 4; ++r) {
        int row = bm + wr * 64 + m * 16 + rg * 4 + r;
        if (sec < 2) {
          int s = pos[row];
#pragma unroll
          for (int n = 0; n < 4; ++n) {
            int hd = hb + n * 16 + cl;
            int d = hd & 63;
            int d2 = d & 31;
            float c = ctab[s * 32 + d2];
            float sn = stab[s * 32 + d2];
            float val = acc[m][n][r];
            float pv = acc[m][n ^ 2][r];
            val = (d < 32) ? (val * c - pv * sn) : (val * c + pv * sn);
            if (sec == 0) val *= 0.125f;
            dst[(size_t)row * HH + hd] = (f16)val;
          }
        } else {
#pragma unroll
          for (int n = 0; n < 4; ++n)
            dst[(size_t)row * HH + hb + n * 16 + cl] = (f16)acc[m][n][r];
        }
      }
  }
}

// ---------------- MFMA sliding-window attention --------------------------
// Block: (b, h, 64-query tile). Window keys: [q0-64, q0+127] = 192 rows.
#define AQT 64
#define AKT 192
#define KP 72     // K/Q row pad (f16): 144 B rows
#define VP 200    // Vt / P row pad: 400 B rows

__global__ __launch_bounds__(256)
void attn_kernel(const f16* __restrict__ qg, const f16* __restrict__ kg,
                 const f16* __restrict__ vg, f16* __restrict__ og) {
  __shared__ __align__(16) f16 Qs[AQT][KP];     // 9216 B
  __shared__ __align__(16) f16 Ks[AKT][KP];     // 27648 B, reused for P[64][VP]
  __shared__ __align__(16) f16 Vs[64][VP];      // 25600 B (transposed V)
  __shared__ float sums[AQT];

  const int tid = threadIdx.x;
  const int lane = tid & 63;
  const int wq = tid >> 6;
  const int l15 = lane & 15, g = lane >> 4;
  const int blk = blockIdx.x;
  const int qt = blk % (SS / AQT);
  const int h = (blk / (SS / AQT)) % NHEADS;
  const int b = blk / ((SS / AQT) * NHEADS);
  const int q0 = qt * AQT;
  const int kbase = q0 - 64;

  // ---- stage Q (64x64), K (192x64), V transposed (64x192) ----
#pragma unroll
  for (int i = 0; i < 2; ++i) {
    int idx = tid + i * 256;
    int r = idx >> 3, ch = idx & 7;
    f16x8 v = *reinterpret_cast<const f16x8*>(
        &qg[((size_t)(b * SS + q0 + r)) * HH + h * 64 + ch * 8]);
    *reinterpret_cast<f16x8*>(&Qs[r][ch * 8]) = v;
  }
#pragma unroll
  for (int i = 0; i < 6; ++i) {
    int idx = tid + i * 256;
    int r = idx >> 3, ch = idx & 7;
    int kglob = kbase + r;
    f16x8 v = {};
    if (kglob >= 0 && kglob < SS)
      v = *reinterpret_cast<const f16x8*>(
          &kg[((size_t)(b * SS + kglob)) * HH + h * 64 + ch * 8]);
    *reinterpret_cast<f16x8*>(&Ks[r][ch * 8]) = v;
  }
#pragma unroll
  for (int i = 0; i < 6; ++i) {
    int idx = tid + i * 256;
    int r = idx >> 3, ch = idx & 7;
    int kglob = kbase + r;
    f16x8 v = {};
    if (kglob >= 0 && kglob < SS)
      v = *reinterpret_cast<const f16x8*>(
          &vg[((size_t)(b * SS + kglob)) * HH + h * 64 + ch * 8]);
#pragma unroll
    for (int j = 0; j < 8; ++j) Vs[ch * 8 + j][r] = v[j];
  }
  __syncthreads();

  // ---- S^T = K . Q^T  (A=K rows=keys, B=Q cols=wave's 16 q) ----
  f32x4 accs[12] = {};
#pragma unroll
  for (int kd = 0; kd < 2; ++kd) {
    f16x8 bq = *reinterpret_cast<const f16x8*>(&Qs[wq * 16 + l15][kd * 32 + g * 8]);
#pragma unroll
    for (int f = 0; f < 12; ++f) {
      f16x8 ak = *reinterpret_cast<const f16x8*>(&Ks[f * 16 + l15][kd * 32 + g * 8]);
      accs[f] = __builtin_amdgcn_mfma_f32_16x16x32_f16(ak, bq, accs[f], 0, 0, 0);
    }
  }
  __syncthreads();   // everyone done reading Ks; it becomes P storage

  // ---- softmax over keys; lane owns column q = wq*16+l15 ----
  const int qloc = wq * 16 + l15;
  float mx = -1e30f;
#pragma unroll
  for (int f = 0; f < 12; ++f)
#pragma unroll
    for (int r = 0; r < 4; ++r) {
      int key = f * 16 + g * 4 + r;
      int kglob = kbase + key;
      bool valid = (key >= qloc) && (key <= qloc + 128) && (kglob >= 0) && (kglob < SS);
      float s = valid ? accs[f][r] : -1e30f;
      accs[f][r] = s;
      mx = fmaxf(mx, s);
    }
  mx = fmaxf(mx, __shfl_xor(mx, 16));
  mx = fmaxf(mx, __shfl_xor(mx, 32));
  f16* Ps = &Ks[0][0];   // P[q][VP], wave-private rows
  float sum = 0.f;
#pragma unroll
  for (int f = 0; f < 12; ++f) {
    float p0 = __expf(accs[f][0] - mx);
    float p1 = __expf(accs[f][1] - mx);
    float p2 = __expf(accs[f][2] - mx);
    float p3 = __expf(accs[f][3] - mx);
    sum += (p0 + p1) + (p2 + p3);
    f16x4 pk;
    pk[0] = (f16)p0; pk[1] = (f16)p1; pk[2] = (f16)p2; pk[3] = (f16)p3;
    *reinterpret_cast<f16x4*>(&Ps[(size_t)qloc * VP + f * 16 + g * 4]) = pk;
  }
  sum += __shfl_xor(sum, 16);
  sum += __shfl_xor(sum, 32);
  if (g == 0) sums[qloc] = sum;
  // no barrier needed: P rows + sums are wave-private, Vs staged pre-bar1

  // ---- O = P . V  (A=P rows=q, B=Vt cols=d) ----
  f32x4 acco[4] = {};
#pragma unroll
  for (int ks = 0; ks < 6; ++ks) {
    f16x8 pa = *reinterpret_cast<const f16x8*>(&Ps[(size_t)(wq * 16 + l15) * VP + ks * 32 + g * 8]);
#pragma unroll
    for (int n = 0; n < 4; ++n) {
      f16x8 bv = *reinterpret_cast<const f16x8*>(&Vs[n * 16 + l15][ks * 32 + g * 8]);
      acco[n] = __builtin_amdgcn_mfma_f32_16x16x32_f16(pa, bv, acco[n], 0, 0, 0);
    }
  }
#pragma unroll
  for (int r = 0; r < 4; ++r) {
    int qo = wq * 16 + g * 4 + r;
    float inv = 1.0f / sums[qo];
    size_t base = ((size_t)(b * SS + q0 + qo)) * HH + h * 64;
#pragma unroll
    for (int n = 0; n < 4; ++n)
      og[base + n * 16 + l15] = (f16)(acco[n][r] * inv);
  }
}

extern "C" void kernel_launch(void* const* d_in, const int* in_sizes, int n_in,
                              void* d_out, int out_size, void* d_ws, size_t ws_size,
                              hipStream_t stream) {
  const float* hs = (const float*)d_in[0];
  const int* pos = (const int*)d_in[3];
  const float* Wqkv = (const float*)d_in[4];
  const float* Wo = (const float*)d_in[5];
  float* out = (float*)d_out;

  uint8_t* ws = (uint8_t*)d_ws;
  size_t off = 0;
  float* ctab = (float*)(ws + off); off += (size_t)SS * 32 * 4;
  float* stab = (float*)(ws + off); off += (size_t)SS * 32 * 4;
  f16* hs16 = (f16*)(ws + off); off += (size_t)MTOT * HH * 2;
  f16* wq16 = (f16*)(ws + off); off += (size_t)NQKV * HH * 2;
  f16* wo16 = (f16*)(ws + off); off += (size_t)HH * HH * 2;
  f16* qf = (f16*)(ws + off); off += (size_t)MTOT * HH * 2;
  f16* kf = (f16*)(ws + off); off += (size_t)MTOT * HH * 2;
  f16* vf = (f16*)(ws + off); off += (size_t)MTOT * HH * 2;
  f16* af = (f16*)(ws + off); off += (size_t)MTOT * HH * 2;

  cvt_kernel<<<(MTOT * HH / 4 + 255) / 256, 256, 0, stream>>>(hs, hs16, MTOT * HH / 4);
  cvt_kernel<<<(NQKV * HH / 4 + 255) / 256, 256, 0, stream>>>(Wqkv, wq16, NQKV * HH / 4);
  cvt_kernel<<<(HH * HH / 4 + 255) / 256, 256, 0, stream>>>(Wo, wo16, HH * HH / 4);
  rope_table_kernel<<<(SS * 32 + 255) / 256, 256, 0, stream>>>(ctab, stab);

  // 1. QKV projection + fused RoPE/scale -> q/k/v f16
  gemm_f16<1><<<(MTOT / 128) * (NQKV / 128), 256, 0, stream>>>(
      hs16, wq16, nullptr, qf, kf, vf, pos, ctab, stab, MTOT / 128, NQKV, HH);
  // 2. Attention
  attn_kernel<<<BB * NHEADS * (SS / AQT), 256, 0, stream>>>(qf, kf, vf, af);
  // 3. Output projection
  gemm_f16<0><<<(MTOT / 128) * (HH / 128), 256, 0, stream>>>(
      af, wo16, out, nullptr, nullptr, nullptr, nullptr, nullptr, nullptr,
      MTOT / 128, HH, HH);
}